// Round 5
// baseline (513.454 us; speedup 1.0000x reference)
//
#include <hip/hip_runtime.h>

#define DEVINL __device__ __forceinline__

typedef __attribute__((ext_vector_type(8))) short short8;
typedef __attribute__((ext_vector_type(4))) float floatx4;
typedef __attribute__((ext_vector_type(2))) unsigned uintx2;

DEVINL unsigned short f2bf(float f){
  unsigned u = __builtin_bit_cast(unsigned, f);
  u += 0x7FFFu + ((u >> 16) & 1u);          // RNE
  return (unsigned short)(u >> 16);
}
DEVINL unsigned pk2(float a, float b){      // low16=bf16(a), high16=bf16(b)
  unsigned ua = __builtin_bit_cast(unsigned, a);
  unsigned ub = __builtin_bit_cast(unsigned, b);
  ua += 0x7FFFu + ((ua >> 16) & 1u);
  ub += 0x7FFFu + ((ub >> 16) & 1u);
  return (ua >> 16) | (ub & 0xFFFF0000u);
}
// round-half-up bf16 pack of (a,b) via v_perm
DEVINL unsigned pkfast(float a, float b){
  unsigned ua = __builtin_bit_cast(unsigned, a) + 0x8000u;
  unsigned ub = __builtin_bit_cast(unsigned, b) + 0x8000u;
  return __builtin_amdgcn_perm(ub, ua, 0x07060302u);
}
// single-instr pack where available (gfx950 v_cvt_pk_bf16_f32)
DEVINL unsigned pkbf(float a, float b){
#if defined(__has_builtin)
#if __has_builtin(__builtin_amdgcn_cvt_pk_bf16_f32)
  typedef __attribute__((ext_vector_type(2))) __bf16 bf16x2_t;
  bf16x2_t r = __builtin_amdgcn_cvt_pk_bf16_f32(a, b);
  return __builtin_bit_cast(unsigned, r);
#else
  return pkfast(a, b);
#endif
#else
  return pkfast(a, b);
#endif
}
DEVINL float bf2f(unsigned short h){
  unsigned u = ((unsigned)h) << 16;
  return __builtin_bit_cast(float, u);
}
DEVINL void gload_lds16(const void* g, void* l){
  __builtin_amdgcn_global_load_lds((const __attribute__((address_space(1))) void*)g,
                                   (__attribute__((address_space(3))) void*)l, 16, 0, 0);
}
// key permutation: St C-layout register <-> PV B-operand k' index
DEVINL int perm2(int k){
  return (((k >> 4) & 1) << 5) | (((k >> 2) & 3) << 3) | (((k >> 5) & 1) << 2) | (k & 3);
}

// ---------------- dtype detector ----------------
__global__ void k_detect(const unsigned* __restrict__ w, int* __restrict__ flag){
  __shared__ int cnt;
  if (threadIdx.x == 0) cnt = 0;
  __syncthreads();
  int c = 0;
  for (int i = threadIdx.x; i < 1024; i += 256){
    unsigned e = (w[i] >> 7) & 0xFFu;
    c += (e >= 120u && e <= 132u) ? 1 : 0;
  }
  atomicAdd(&cnt, c);
  __syncthreads();
  if (threadIdx.x == 0) *flag = (cnt > 512) ? 1 : 0;
}

// ---------------- conversions ----------------
__global__ void k_conv_bf16(const void* __restrict__ src, unsigned short* __restrict__ dst,
                            int n, const int* __restrict__ flag){
  int i = (blockIdx.x * 256 + threadIdx.x) * 8;
  if (i >= n) return;
  if (*flag){
    ((uint4*)dst)[i >> 3] = ((const uint4*)src)[i >> 3];
  } else {
    const float* s = (const float*)src;
    short8 v;
    #pragma unroll
    for (int j = 0; j < 8; j++) v[j] = (short)f2bf(s[i + j]);
    *(short8*)(dst + i) = v;
  }
}

// 4 weights [K][N] -> [N][K] bf16, one launch (z selects matrix)
__global__ void k_conv_wT4(const void* __restrict__ s0, const void* __restrict__ s1,
                           const void* __restrict__ s2, const void* __restrict__ s3,
                           unsigned short* __restrict__ d0, unsigned short* __restrict__ d1,
                           unsigned short* __restrict__ d2, unsigned short* __restrict__ d3,
                           const int* __restrict__ flag){
  __shared__ float tile[32][33];
  const void* src; unsigned short* dst;
  switch (blockIdx.z){
    case 0: src = s0; dst = d0; break;
    case 1: src = s1; dst = d1; break;
    case 2: src = s2; dst = d2; break;
    default: src = s3; dst = d3; break;
  }
  const int tx = threadIdx.x & 31, ty = threadIdx.x >> 5;
  const int bx = blockIdx.x, by = blockIdx.y;
  const int isbf = *flag;
  #pragma unroll
  for (int r = 0; r < 32; r += 8){
    int k = by*32 + ty + r, n = bx*32 + tx;
    float v = isbf ? bf2f(((const unsigned short*)src)[k*1024 + n])
                   : ((const float*)src)[k*1024 + n];
    tile[ty + r][tx] = v;
  }
  __syncthreads();
  #pragma unroll
  for (int r = 0; r < 32; r += 8){
    int n = bx*32 + ty + r, k = by*32 + tx;
    dst[n*1024 + k] = f2bf(tile[tx][ty + r]);
  }
}

// 4 biases -> one contiguous float[4096]
__global__ void k_conv_b4(const void* __restrict__ s0, const void* __restrict__ s1,
                          const void* __restrict__ s2, const void* __restrict__ s3,
                          float* __restrict__ dst, const int* __restrict__ flag){
  int i = blockIdx.x * 256 + threadIdx.x;
  if (i >= 4096) return;
  int z = i >> 10, j = i & 1023;
  const void* s = (z == 0) ? s0 : (z == 1) ? s1 : (z == 2) ? s2 : s3;
  dst[i] = (*flag) ? bf2f(((const unsigned short*)s)[j]) : ((const float*)s)[j];
}

// ---------------- m97-style bf16 GEMM, A[M,K] x Bt[N,K]^T + bias ----------------
// MODE 3: fused QKV, N=3072. n>>10 selects dst:
//   0 -> Q [h][s][d^sw] (*scale)   1 -> K [h][s][d^sw]   2 -> V [h][d][s'^sw] (key-permuted)
//   where ^sw = XOR of the 16B-chunk index with (row&7) -- pre-swizzled for LDS.
// MODE 1: dst = C0, [m][n]; fp32 or bf16 per *flagp
template<int MODE>
__global__ __launch_bounds__(256, 2) void k_gemm(
    const unsigned short* __restrict__ A, const unsigned short* __restrict__ Bt,
    const float* __restrict__ bias, void* __restrict__ C0, void* __restrict__ C1,
    void* __restrict__ C2, const int* __restrict__ flagp, float scale)
{
  const int K = 1024;
  __shared__ __align__(16) unsigned short As[128*32];
  __shared__ __align__(16) unsigned short Bs[128*32];
  const int tid = threadIdx.x;
  const int lane = tid & 63, wave = tid >> 6;
  const int quad = lane >> 4, l15 = lane & 15;
  const int m0 = blockIdx.x * 128, n0 = blockIdx.y * 128;
  const int wm = (wave >> 1) * 64, wn = (wave & 1) * 64;
  const floatx4 fzero = {0.f, 0.f, 0.f, 0.f};
  floatx4 acc[4][4];
  #pragma unroll
  for (int i = 0; i < 4; i++)
    #pragma unroll
    for (int j = 0; j < 4; j++) acc[i][j] = fzero;

  for (int k0 = 0; k0 < K; k0 += 32){
    __syncthreads();
    #pragma unroll
    for (int rep = 0; rep < 2; rep++){
      int idx = tid + rep*256;
      int row = idx >> 2, c = idx & 3;
      gload_lds16(A  + (size_t)(m0 + row)*K + (k0 + c*8), &As[idx*8]);
      gload_lds16(Bt + (size_t)(n0 + row)*K + (k0 + c*8), &Bs[idx*8]);
    }
    asm volatile("s_waitcnt vmcnt(0)" ::: "memory");
    __syncthreads();
    short8 af[4], bf[4];
    #pragma unroll
    for (int i = 0; i < 4; i++) af[i] = *(const short8*)&As[(wm + i*16 + l15)*32 + quad*8];
    #pragma unroll
    for (int j = 0; j < 4; j++) bf[j] = *(const short8*)&Bs[(wn + j*16 + l15)*32 + quad*8];
    #pragma unroll
    for (int i = 0; i < 4; i++)
      #pragma unroll
      for (int j = 0; j < 4; j++)
        acc[i][j] = __builtin_amdgcn_mfma_f32_16x16x32_bf16(af[i], bf[j], acc[i][j], 0, 0, 0);
  }

  float bs[4];
  #pragma unroll
  for (int j = 0; j < 4; j++) bs[j] = bias[n0 + wn + j*16 + l15];
  const int useBf = (MODE == 1) ? *flagp : 1;
  #pragma unroll
  for (int i = 0; i < 4; i++){
    #pragma unroll
    for (int j = 0; j < 4; j++){
      int n = n0 + wn + j*16 + l15;
      #pragma unroll
      for (int r = 0; r < 4; r++){
        int m = m0 + wm + i*16 + quad*4 + r;      // C/D: col=lane&15, row=quad*4+reg
        float v = acc[i][j][r] + bs[j];
        if (MODE == 3){
          int sel = n >> 10, nn = n & 1023;       // wave-uniform per (i,j)
          if (sel == 0){
            int dd = (nn & 63) ^ ((m & 7) << 3);  // pre-swizzle chunk by s&7
            ((unsigned short*)C0)[((size_t)(nn >> 6)*8192 + m)*64 + dd] = f2bf(v * scale);
          } else if (sel == 1){
            int dd = (nn & 63) ^ ((m & 7) << 3);
            ((unsigned short*)C1)[((size_t)(nn >> 6)*8192 + m)*64 + dd] = f2bf(v);
          } else {
            int s2 = perm2(m & 63) ^ ((nn & 7) << 3);  // key-perm then swizzle by d&7
            ((unsigned short*)C2)[(size_t)nn*8192 + (m & ~63) + s2] = f2bf(v);
          }
        } else {
          if (useBf) ((unsigned short*)C0)[(size_t)m*1024 + n] = f2bf(v);
          else       ((float*)C0)[(size_t)m*1024 + n] = v;
        }
      }
    }
  }
}

// ---------------- ring attention: 512 threads, 8 waves x 32q, 4 waves/SIMD ----------------
// Q/K/V pre-swizzled in global so tiles are verbatim LDS images (global_load_lds).
// Row-sum l via ones-MFMA; St zero-init folded into first MFMA (C = persistent zero).
__global__ __launch_bounds__(512, 4) void k_attn(
    const unsigned short* __restrict__ Qg, const unsigned short* __restrict__ Kg,
    const unsigned short* __restrict__ Vg, unsigned short* __restrict__ ctx)
{
  __shared__ __align__(16) unsigned short Qs[256*64];
  __shared__ __align__(16) unsigned short Ks[2][64*64];
  __shared__ __align__(16) unsigned short Vs[2][64*64];
  const int tid = threadIdx.x, lane = tid & 63, wave = tid >> 6;   // wave 0..7
  const int quad = lane >> 4, l15 = lane & 15;
  const int bid = blockIdx.x;
  const int xcd = bid & 7, slot = bid >> 3;
  const int h = xcd*2 + (slot >> 5);
  const int rem = slot & 31, rchunk = rem >> 3, qt = rem & 7;
  const int sq0 = rchunk*2048 + qt*256;
  const char* Qbase = (const char*)(Qg + (size_t)h*8192*64 + (size_t)sq0*64);
  const char* Kbase = (const char*)(Kg + (size_t)h*8192*64);     // [s][d^sw] rows 128B
  const char* Vbase = (const char*)(Vg + (size_t)h*8192*64);     // [d][s'^sw] rows 16KB
  const int wq0 = wave * 32;
  const floatx4 fz = {0.f, 0.f, 0.f, 0.f};                       // persistent zero C

  // per-thread staging offsets (512 threads x 16B = one 8KB tile per instr)
  const size_t voff = (size_t)(tid >> 3)*16384 + (size_t)(tid & 7)*16;

  auto stage = [&](int buf, int kvs){
    gload_lds16(Kbase + (size_t)kvs*128 + tid*16, (char*)Ks[buf] + tid*16);
    gload_lds16(Vbase + (size_t)kvs*2 + voff,     (char*)Vs[buf] + tid*16);
  };

  // stage Q (verbatim 32KB) + first K/V tile
  #pragma unroll
  for (int rep = 0; rep < 4; rep++){
    int idx = tid + rep*512;
    gload_lds16(Qbase + idx*16, (char*)Qs + idx*16);
  }
  stage(0, rchunk*2048);
  asm volatile("s_waitcnt vmcnt(0)" ::: "memory");
  __syncthreads();

  short8 qf[2][2];                                     // B-operand fragments
  #pragma unroll
  for (int mi = 0; mi < 2; mi++)
    #pragma unroll
    for (int ks = 0; ks < 2; ks++){
      int row = wq0 + mi*16 + l15;
      qf[mi][ks] = *(const short8*)&Qs[row*64 + (((ks*4 + quad) ^ (row & 7)))*8];
    }

  short8 ones;
  #pragma unroll
  for (int j = 0; j < 8; j++) ones[j] = (short)0x3F80;  // bf16 1.0

  floatx4 Of[2][4];
  #pragma unroll
  for (int mi = 0; mi < 2; mi++)
    #pragma unroll
    for (int di = 0; di < 4; di++) Of[mi][di] = fz;

  for (int i = 0; i < 4; i++){
    floatx4 Oc[2][4], Ol[2];
    #pragma unroll
    for (int mi = 0; mi < 2; mi++){
      Ol[mi] = fz;
      #pragma unroll
      for (int di = 0; di < 4; di++) Oc[mi][di] = fz;
    }

    for (int kt = 0; kt < 32; kt++){
      const int t = i*32 + kt, cur = t & 1;
      asm volatile("s_waitcnt vmcnt(0)" ::: "memory");  // tile t landed
      __syncthreads();                                  // + prev readers of buf[cur^1] done
      if (t < 127){
        int t1 = t + 1;
        int kvs = ((rchunk + (t1 >> 5)) & 3)*2048 + (t1 & 31)*64;
        stage(cur ^ 1, kvs);                            // async, lands during compute
      }

      // S^T = K Q^T (C of first MFMA = persistent zero reg), exp2, packed P
      short8 pf[2][2];
      #pragma unroll
      for (int mi = 0; mi < 2; mi++){
        floatx4 St[4];
        #pragma unroll
        for (int ni = 0; ni < 4; ni++){
          int krow = ni*16 + l15;
          short8 kf = *(const short8*)&Ks[cur][krow*64 + ((quad ^ (krow & 7)))*8];
          St[ni] = __builtin_amdgcn_mfma_f32_16x16x32_bf16(kf, qf[mi][0], fz, 0, 0, 0);
        }
        #pragma unroll
        for (int ni = 0; ni < 4; ni++){
          int krow = ni*16 + l15;
          short8 kf = *(const short8*)&Ks[cur][krow*64 + (((4 + quad) ^ (krow & 7)))*8];
          St[ni] = __builtin_amdgcn_mfma_f32_16x16x32_bf16(kf, qf[mi][1], St[ni], 0, 0, 0);
        }
        #pragma unroll
        for (int ni = 0; ni < 4; ni++)
          #pragma unroll
          for (int r = 0; r < 4; r++)
            St[ni][r] = __builtin_amdgcn_exp2f(St[ni][r]);
        #pragma unroll
        for (int ks = 0; ks < 2; ks++){
          uintx2 lo, hi;  // 8 shorts: e[ks][0..3], e[ks+2][0..3]
          lo[0] = pkbf(St[ks  ][0], St[ks  ][1]);
          lo[1] = pkbf(St[ks  ][2], St[ks  ][3]);
          hi[0] = pkbf(St[2+ks][0], St[2+ks][1]);
          hi[1] = pkbf(St[2+ks][2], St[2+ks][3]);
          union { uintx2 u[2]; short8 s; } cv;
          cv.u[0] = lo; cv.u[1] = hi;
          pf[mi][ks] = cv.s;
        }
      }

      // O^T += V^T P^T ; l += ones^T P^T (row-sum via MFMA pipe)
      #pragma unroll
      for (int ks = 0; ks < 2; ks++){
        #pragma unroll
        for (int di = 0; di < 4; di++){
          int vrow = di*16 + l15;
          short8 vf = *(const short8*)&Vs[cur][vrow*64 + (((ks*4 + quad) ^ (vrow & 7)))*8];
          #pragma unroll
          for (int mi = 0; mi < 2; mi++)
            Oc[mi][di] = __builtin_amdgcn_mfma_f32_16x16x32_bf16(vf, pf[mi][ks], Oc[mi][di], 0, 0, 0);
        }
        #pragma unroll
        for (int mi = 0; mi < 2; mi++)
          Ol[mi] = __builtin_amdgcn_mfma_f32_16x16x32_bf16(ones, pf[mi][ks], Ol[mi], 0, 0, 0);
      }
    }

    // fold chunk: Of += Oc / l   (Ol rows all equal the complete per-q sum)
    #pragma unroll
    for (int mi = 0; mi < 2; mi++){
      float inv = __builtin_amdgcn_rcpf(Ol[mi][0]);
      #pragma unroll
      for (int di = 0; di < 4; di++)
        #pragma unroll
        for (int r = 0; r < 4; r++) Of[mi][di][r] += Oc[mi][di][r] * inv;
    }
  }

  // ctx[q][h*64+d] = Of/SP
  #pragma unroll
  for (int mi = 0; mi < 2; mi++){
    int q = sq0 + wq0 + mi*16 + l15;
    #pragma unroll
    for (int di = 0; di < 4; di++){
      uintx2 w;
      w[0] = pk2(Of[mi][di][0]*0.25f, Of[mi][di][1]*0.25f);
      w[1] = pk2(Of[mi][di][2]*0.25f, Of[mi][di][3]*0.25f);
      *(uintx2*)&ctx[(size_t)q*1024 + h*64 + di*16 + quad*4] = w;
    }
  }
}

// ---------------- host ----------------
extern "C" void kernel_launch(void* const* d_in, const int* in_sizes, int n_in,
                              void* d_out, int out_size, void* d_ws, size_t ws_size,
                              hipStream_t stream)
{
  (void)in_sizes; (void)n_in; (void)out_size; (void)ws_size;
  char* ws = (char*)d_ws;
  size_t off = 0;
  auto alloc = [&](size_t bytes) -> char* {
    char* p = ws + off;
    off = (off + bytes + 255) & ~(size_t)255;
    return p;
  };
  int* flag            = (int*)alloc(4);
  unsigned short* hsb  = (unsigned short*)alloc((size_t)8192*1024*2);
  unsigned short* wqt  = (unsigned short*)alloc((size_t)1024*1024*2);
  unsigned short* wkt  = (unsigned short*)alloc((size_t)1024*1024*2);
  unsigned short* wvt  = (unsigned short*)alloc((size_t)1024*1024*2);
  unsigned short* wot  = (unsigned short*)alloc((size_t)1024*1024*2);
  float* biasAll       = (float*)alloc(4096*4);                        // q,k,v,o contiguous
  unsigned short* Qb   = (unsigned short*)alloc((size_t)16*8192*64*2); // [h][s][d^sw] *Cs
  unsigned short* Kb   = (unsigned short*)alloc((size_t)16*8192*64*2); // [h][s][d^sw]
  unsigned short* Vb   = (unsigned short*)alloc((size_t)16*8192*64*2); // [h][d][s'^sw] permuted
  unsigned short* ctxb = (unsigned short*)alloc((size_t)8192*1024*2);  // [s][hd]

  k_detect<<<1, 256, 0, stream>>>((const unsigned*)d_in[0], flag);
  k_conv_bf16<<<4096, 256, 0, stream>>>(d_in[0], hsb, 8192*1024, flag);
  k_conv_wT4<<<dim3(32,32,4), 256, 0, stream>>>(d_in[1], d_in[3], d_in[5], d_in[7],
                                                wqt, wkt, wvt, wot, flag);
  k_conv_b4<<<16, 256, 0, stream>>>(d_in[2], d_in[4], d_in[6], d_in[8], biasAll, flag);

  const float Cs = 0.18033688011112042f;   // (1/8)*log2(e), folded into Q
  // fused QKV projection: N=3072
  k_gemm<3><<<dim3(64, 24), 256, 0, stream>>>(hsb, wqt, biasAll, Qb, Kb, Vb, nullptr, Cs);

  k_attn<<<512, 512, 0, stream>>>(Qb, Kb, Vb, ctxb);

  k_gemm<1><<<dim3(64, 8), 256, 0, stream>>>(ctxb, wot, biasAll + 3072, d_out,
                                             nullptr, nullptr, flag, 1.0f);
}

// Round 6
// 487.675 us; speedup vs baseline: 1.0529x; 1.0529x over previous
//
#include <hip/hip_runtime.h>

#define DEVINL __device__ __forceinline__

typedef __attribute__((ext_vector_type(8))) short short8;
typedef __attribute__((ext_vector_type(4))) float floatx4;
typedef __attribute__((ext_vector_type(2))) unsigned uintx2;

DEVINL unsigned short f2bf(float f){
  unsigned u = __builtin_bit_cast(unsigned, f);
  u += 0x7FFFu + ((u >> 16) & 1u);          // RNE
  return (unsigned short)(u >> 16);
}
DEVINL unsigned pk2(float a, float b){      // low16=bf16(a), high16=bf16(b)
  unsigned ua = __builtin_bit_cast(unsigned, a);
  unsigned ub = __builtin_bit_cast(unsigned, b);
  ua += 0x7FFFu + ((ua >> 16) & 1u);
  ub += 0x7FFFu + ((ub >> 16) & 1u);
  return (ua >> 16) | (ub & 0xFFFF0000u);
}
// round-half-up bf16 pack of (a,b) via v_perm
DEVINL unsigned pkfast(float a, float b){
  unsigned ua = __builtin_bit_cast(unsigned, a) + 0x8000u;
  unsigned ub = __builtin_bit_cast(unsigned, b) + 0x8000u;
  return __builtin_amdgcn_perm(ub, ua, 0x07060302u);
}
// single-instr pack where available (gfx950 v_cvt_pk_bf16_f32)
DEVINL unsigned pkbf(float a, float b){
#if defined(__has_builtin)
#if __has_builtin(__builtin_amdgcn_cvt_pk_bf16_f32)
  typedef __attribute__((ext_vector_type(2))) __bf16 bf16x2_t;
  bf16x2_t r = __builtin_amdgcn_cvt_pk_bf16_f32(a, b);
  return __builtin_bit_cast(unsigned, r);
#else
  return pkfast(a, b);
#endif
#else
  return pkfast(a, b);
#endif
}
DEVINL float bf2f(unsigned short h){
  unsigned u = ((unsigned)h) << 16;
  return __builtin_bit_cast(float, u);
}
DEVINL void gload_lds16(const void* g, void* l){
  __builtin_amdgcn_global_load_lds((const __attribute__((address_space(1))) void*)g,
                                   (__attribute__((address_space(3))) void*)l, 16, 0, 0);
}
// key permutation: St C-layout register <-> PV B-operand k' index
DEVINL int perm2(int k){
  return (((k >> 4) & 1) << 5) | (((k >> 2) & 3) << 3) | (((k >> 5) & 1) << 2) | (k & 3);
}

// ---------------- dtype detector ----------------
__global__ void k_detect(const unsigned* __restrict__ w, int* __restrict__ flag){
  __shared__ int cnt;
  if (threadIdx.x == 0) cnt = 0;
  __syncthreads();
  int c = 0;
  for (int i = threadIdx.x; i < 1024; i += 256){
    unsigned e = (w[i] >> 7) & 0xFFu;
    c += (e >= 120u && e <= 132u) ? 1 : 0;
  }
  atomicAdd(&cnt, c);
  __syncthreads();
  if (threadIdx.x == 0) *flag = (cnt > 512) ? 1 : 0;
}

// ---------------- conversions ----------------
__global__ void k_conv_bf16(const void* __restrict__ src, unsigned short* __restrict__ dst,
                            int n, const int* __restrict__ flag){
  int i = (blockIdx.x * 256 + threadIdx.x) * 8;
  if (i >= n) return;
  if (*flag){
    ((uint4*)dst)[i >> 3] = ((const uint4*)src)[i >> 3];
  } else {
    const float* s = (const float*)src;
    short8 v;
    #pragma unroll
    for (int j = 0; j < 8; j++) v[j] = (short)f2bf(s[i + j]);
    *(short8*)(dst + i) = v;
  }
}

// 4 weights [K][N] -> [N][K] bf16, one launch (z selects matrix)
__global__ void k_conv_wT4(const void* __restrict__ s0, const void* __restrict__ s1,
                           const void* __restrict__ s2, const void* __restrict__ s3,
                           unsigned short* __restrict__ d0, unsigned short* __restrict__ d1,
                           unsigned short* __restrict__ d2, unsigned short* __restrict__ d3,
                           const int* __restrict__ flag){
  __shared__ float tile[32][33];
  const void* src; unsigned short* dst;
  switch (blockIdx.z){
    case 0: src = s0; dst = d0; break;
    case 1: src = s1; dst = d1; break;
    case 2: src = s2; dst = d2; break;
    default: src = s3; dst = d3; break;
  }
  const int tx = threadIdx.x & 31, ty = threadIdx.x >> 5;
  const int bx = blockIdx.x, by = blockIdx.y;
  const int isbf = *flag;
  #pragma unroll
  for (int r = 0; r < 32; r += 8){
    int k = by*32 + ty + r, n = bx*32 + tx;
    float v = isbf ? bf2f(((const unsigned short*)src)[k*1024 + n])
                   : ((const float*)src)[k*1024 + n];
    tile[ty + r][tx] = v;
  }
  __syncthreads();
  #pragma unroll
  for (int r = 0; r < 32; r += 8){
    int n = bx*32 + ty + r, k = by*32 + tx;
    dst[n*1024 + k] = f2bf(tile[tx][ty + r]);
  }
}

// 4 biases -> one contiguous float[4096]
__global__ void k_conv_b4(const void* __restrict__ s0, const void* __restrict__ s1,
                          const void* __restrict__ s2, const void* __restrict__ s3,
                          float* __restrict__ dst, const int* __restrict__ flag){
  int i = blockIdx.x * 256 + threadIdx.x;
  if (i >= 4096) return;
  int z = i >> 10, j = i & 1023;
  const void* s = (z == 0) ? s0 : (z == 1) ? s1 : (z == 2) ? s2 : s3;
  dst[i] = (*flag) ? bf2f(((const unsigned short*)s)[j]) : ((const float*)s)[j];
}

// ---------------- m97-style bf16 GEMM, A[M,K] x Bt[N,K]^T + bias ----------------
// MODE 3: fused QKV, N=3072. n>>10 selects dst:
//   0 -> Q [h][s][d^sw] (*scale)   1 -> K [h][s][d^sw]   2 -> V [h][d][s'^sw] (key-permuted)
// MODE 1: dst = C0, [m][n]; fp32 or bf16 per *flagp
template<int MODE>
__global__ __launch_bounds__(256, 2) void k_gemm(
    const unsigned short* __restrict__ A, const unsigned short* __restrict__ Bt,
    const float* __restrict__ bias, void* __restrict__ C0, void* __restrict__ C1,
    void* __restrict__ C2, const int* __restrict__ flagp, float scale)
{
  const int K = 1024;
  __shared__ __align__(16) unsigned short As[128*32];
  __shared__ __align__(16) unsigned short Bs[128*32];
  const int tid = threadIdx.x;
  const int lane = tid & 63, wave = tid >> 6;
  const int quad = lane >> 4, l15 = lane & 15;
  const int m0 = blockIdx.x * 128, n0 = blockIdx.y * 128;
  const int wm = (wave >> 1) * 64, wn = (wave & 1) * 64;
  const floatx4 fzero = {0.f, 0.f, 0.f, 0.f};
  floatx4 acc[4][4];
  #pragma unroll
  for (int i = 0; i < 4; i++)
    #pragma unroll
    for (int j = 0; j < 4; j++) acc[i][j] = fzero;

  for (int k0 = 0; k0 < K; k0 += 32){
    __syncthreads();
    #pragma unroll
    for (int rep = 0; rep < 2; rep++){
      int idx = tid + rep*256;
      int row = idx >> 2, c = idx & 3;
      gload_lds16(A  + (size_t)(m0 + row)*K + (k0 + c*8), &As[idx*8]);
      gload_lds16(Bt + (size_t)(n0 + row)*K + (k0 + c*8), &Bs[idx*8]);
    }
    asm volatile("s_waitcnt vmcnt(0)" ::: "memory");
    __syncthreads();
    short8 af[4], bf[4];
    #pragma unroll
    for (int i = 0; i < 4; i++) af[i] = *(const short8*)&As[(wm + i*16 + l15)*32 + quad*8];
    #pragma unroll
    for (int j = 0; j < 4; j++) bf[j] = *(const short8*)&Bs[(wn + j*16 + l15)*32 + quad*8];
    #pragma unroll
    for (int i = 0; i < 4; i++)
      #pragma unroll
      for (int j = 0; j < 4; j++)
        acc[i][j] = __builtin_amdgcn_mfma_f32_16x16x32_bf16(af[i], bf[j], acc[i][j], 0, 0, 0);
  }

  float bs[4];
  #pragma unroll
  for (int j = 0; j < 4; j++) bs[j] = bias[n0 + wn + j*16 + l15];
  const int useBf = (MODE == 1) ? *flagp : 1;
  #pragma unroll
  for (int i = 0; i < 4; i++){
    #pragma unroll
    for (int j = 0; j < 4; j++){
      int n = n0 + wn + j*16 + l15;
      #pragma unroll
      for (int r = 0; r < 4; r++){
        int m = m0 + wm + i*16 + quad*4 + r;      // C/D: col=lane&15, row=quad*4+reg
        float v = acc[i][j][r] + bs[j];
        if (MODE == 3){
          int sel = n >> 10, nn = n & 1023;       // wave-uniform per (i,j)
          if (sel == 0){
            int dd = (nn & 63) ^ ((m & 7) << 3);  // pre-swizzle chunk by s&7
            ((unsigned short*)C0)[((size_t)(nn >> 6)*8192 + m)*64 + dd] = f2bf(v * scale);
          } else if (sel == 1){
            int dd = (nn & 63) ^ ((m & 7) << 3);
            ((unsigned short*)C1)[((size_t)(nn >> 6)*8192 + m)*64 + dd] = f2bf(v);
          } else {
            int s2 = perm2(m & 63) ^ ((nn & 7) << 3);  // key-perm then swizzle by d&7
            ((unsigned short*)C2)[(size_t)nn*8192 + (m & ~63) + s2] = f2bf(v);
          }
        } else {
          if (useBf) ((unsigned short*)C0)[(size_t)m*1024 + n] = f2bf(v);
          else       ((float*)C0)[(size_t)m*1024 + n] = v;
        }
      }
    }
  }
}

// ---------------- ring attention: one (q-tile, ring-chunk) per block ----------------
// 512 threads, 8 waves x 32q, 4 waves/SIMD. No cross-chunk accumulator (Of removed):
// each block writes its chunk's Oc/l/SP partial. ATOMIC=0: fp32 plane per chunk;
// ATOMIC=1: atomicAdd into a zeroed fp32 ctx accumulator (small-ws fallback).
template<int ATOMIC>
__global__ __launch_bounds__(512, 4) void k_attn(
    const unsigned short* __restrict__ Qg, const unsigned short* __restrict__ Kg,
    const unsigned short* __restrict__ Vg, float* __restrict__ outp)
{
  __shared__ __align__(16) unsigned short Qs[256*64];
  __shared__ __align__(16) unsigned short Ks[2][64*64];
  __shared__ __align__(16) unsigned short Vs[2][64*64];
  const int tid = threadIdx.x, lane = tid & 63, wave = tid >> 6;   // wave 0..7
  const int quad = lane >> 4, l15 = lane & 15;
  const int bid = blockIdx.x;
  const int xcd = bid & 7, slot = bid >> 3;          // 2 heads per XCD for K/V L2 locality
  const int h = xcd*2 + (slot >> 7);
  const int rem = slot & 127;
  const int rchunk = rem >> 5, rem2 = rem & 31;
  const int cidx = rem2 >> 3, qt = rem2 & 7;         // ring step, q-subtile
  const int sq0 = rchunk*2048 + qt*256;
  const int kb = ((rchunk + cidx) & 3)*2048;         // this block's kv chunk
  const char* Qbase = (const char*)(Qg + (size_t)h*8192*64 + (size_t)sq0*64);
  const char* Kbase = (const char*)(Kg + (size_t)h*8192*64);     // [s][d^sw] rows 128B
  const char* Vbase = (const char*)(Vg + (size_t)h*8192*64);     // [d][s'^sw] rows 16KB
  const int wq0 = wave * 32;
  const floatx4 fz = {0.f, 0.f, 0.f, 0.f};

  const size_t voff = (size_t)(tid >> 3)*16384 + (size_t)(tid & 7)*16;
  auto stage = [&](int buf, int kvs){
    gload_lds16(Kbase + (size_t)kvs*128 + tid*16, (char*)Ks[buf] + tid*16);
    gload_lds16(Vbase + (size_t)kvs*2 + voff,     (char*)Vs[buf] + tid*16);
  };

  // stage Q (verbatim 32KB) + first K/V tile
  #pragma unroll
  for (int rep = 0; rep < 4; rep++){
    int idx = tid + rep*512;
    gload_lds16(Qbase + idx*16, (char*)Qs + idx*16);
  }
  stage(0, kb);
  asm volatile("s_waitcnt vmcnt(0)" ::: "memory");
  __syncthreads();

  short8 qf[2][2];
  #pragma unroll
  for (int mi = 0; mi < 2; mi++)
    #pragma unroll
    for (int ks = 0; ks < 2; ks++){
      int row = wq0 + mi*16 + l15;
      qf[mi][ks] = *(const short8*)&Qs[row*64 + (((ks*4 + quad) ^ (row & 7)))*8];
    }

  short8 ones;
  #pragma unroll
  for (int j = 0; j < 8; j++) ones[j] = (short)0x3F80;  // bf16 1.0

  floatx4 Oc[2][4], Ol[2];
  #pragma unroll
  for (int mi = 0; mi < 2; mi++){
    Ol[mi] = fz;
    #pragma unroll
    for (int di = 0; di < 4; di++) Oc[mi][di] = fz;
  }

  for (int kt = 0; kt < 32; kt++){
    const int cur = kt & 1;
    asm volatile("s_waitcnt vmcnt(0)" ::: "memory");  // tile kt landed
    __syncthreads();                                  // + prev readers of buf[cur^1] done
    if (kt < 31) stage(cur ^ 1, kb + (kt + 1)*64);    // async, lands during compute

    // S^T = K Q^T (C of first MFMA = persistent zero), exp2, packed P
    short8 pf[2][2];
    #pragma unroll
    for (int mi = 0; mi < 2; mi++){
      floatx4 St[4];
      #pragma unroll
      for (int ni = 0; ni < 4; ni++){
        int krow = ni*16 + l15;
        short8 kf = *(const short8*)&Ks[cur][krow*64 + ((quad ^ (krow & 7)))*8];
        St[ni] = __builtin_amdgcn_mfma_f32_16x16x32_bf16(kf, qf[mi][0], fz, 0, 0, 0);
      }
      #pragma unroll
      for (int ni = 0; ni < 4; ni++){
        int krow = ni*16 + l15;
        short8 kf = *(const short8*)&Ks[cur][krow*64 + (((4 + quad) ^ (krow & 7)))*8];
        St[ni] = __builtin_amdgcn_mfma_f32_16x16x32_bf16(kf, qf[mi][1], St[ni], 0, 0, 0);
      }
      #pragma unroll
      for (int ni = 0; ni < 4; ni++)
        #pragma unroll
        for (int r = 0; r < 4; r++)
          St[ni][r] = __builtin_amdgcn_exp2f(St[ni][r]);
      #pragma unroll
      for (int ks = 0; ks < 2; ks++){
        uintx2 lo, hi;
        lo[0] = pkbf(St[ks  ][0], St[ks  ][1]);
        lo[1] = pkbf(St[ks  ][2], St[ks  ][3]);
        hi[0] = pkbf(St[2+ks][0], St[2+ks][1]);
        hi[1] = pkbf(St[2+ks][2], St[2+ks][3]);
        union { uintx2 u[2]; short8 s; } cv;
        cv.u[0] = lo; cv.u[1] = hi;
        pf[mi][ks] = cv.s;
      }
    }

    // O^T += V^T P^T ; l += ones^T P^T
    #pragma unroll
    for (int ks = 0; ks < 2; ks++){
      #pragma unroll
      for (int di = 0; di < 4; di++){
        int vrow = di*16 + l15;
        short8 vf = *(const short8*)&Vs[cur][vrow*64 + (((ks*4 + quad) ^ (vrow & 7)))*8];
        #pragma unroll
        for (int mi = 0; mi < 2; mi++)
          Oc[mi][di] = __builtin_amdgcn_mfma_f32_16x16x32_bf16(vf, pf[mi][ks], Oc[mi][di], 0, 0, 0);
      }
      #pragma unroll
      for (int mi = 0; mi < 2; mi++)
        Ol[mi] = __builtin_amdgcn_mfma_f32_16x16x32_bf16(ones, pf[mi][ks], Ol[mi], 0, 0, 0);
    }
  }

  // epilogue: partial = Oc / l / SP
  #pragma unroll
  for (int mi = 0; mi < 2; mi++){
    float inv = __builtin_amdgcn_rcpf(Ol[mi][0]) * 0.25f;
    int q = sq0 + wq0 + mi*16 + l15;
    #pragma unroll
    for (int di = 0; di < 4; di++){
      size_t addr = (size_t)q*1024 + h*64 + di*16 + quad*4;
      if (ATOMIC){
        #pragma unroll
        for (int r = 0; r < 4; r++) atomicAdd(&outp[addr + r], Oc[mi][di][r] * inv);
      } else {
        floatx4 v;
        #pragma unroll
        for (int r = 0; r < 4; r++) v[r] = Oc[mi][di][r] * inv;
        *(floatx4*)&outp[(size_t)cidx*8192*1024 + addr] = v;
      }
    }
  }
}

// sum 4 fp32 planes -> bf16 ctx
__global__ void k_redux4(const float* __restrict__ part, unsigned short* __restrict__ ctx){
  const size_t P = (size_t)8192*1024;
  size_t i = ((size_t)blockIdx.x * 256 + threadIdx.x) * 4;
  if (i >= P) return;
  floatx4 a = *(const floatx4*)&part[i];
  floatx4 b = *(const floatx4*)&part[P + i];
  floatx4 c = *(const floatx4*)&part[2*P + i];
  floatx4 d = *(const floatx4*)&part[3*P + i];
  uintx2 w;
  w[0] = pk2(a[0]+b[0]+c[0]+d[0], a[1]+b[1]+c[1]+d[1]);
  w[1] = pk2(a[2]+b[2]+c[2]+d[2], a[3]+b[3]+c[3]+d[3]);
  *(uintx2*)&ctx[i] = w;
}

// fp32 accumulator -> bf16 ctx (atomic fallback)
__global__ void k_cvt1(const float* __restrict__ acc, unsigned short* __restrict__ ctx){
  const size_t P = (size_t)8192*1024;
  size_t i = ((size_t)blockIdx.x * 256 + threadIdx.x) * 4;
  if (i >= P) return;
  floatx4 a = *(const floatx4*)&acc[i];
  uintx2 w;
  w[0] = pk2(a[0], a[1]);
  w[1] = pk2(a[2], a[3]);
  *(uintx2*)&ctx[i] = w;
}

__global__ void k_zero(float* __restrict__ p){
  const size_t P = (size_t)8192*1024;
  size_t i = ((size_t)blockIdx.x * 256 + threadIdx.x) * 4;
  if (i >= P) return;
  floatx4 z = {0.f, 0.f, 0.f, 0.f};
  *(floatx4*)&p[i] = z;
}

// ---------------- host ----------------
extern "C" void kernel_launch(void* const* d_in, const int* in_sizes, int n_in,
                              void* d_out, int out_size, void* d_ws, size_t ws_size,
                              hipStream_t stream)
{
  (void)in_sizes; (void)n_in; (void)out_size;
  char* ws = (char*)d_ws;
  size_t off = 0;
  auto alloc = [&](size_t bytes) -> char* {
    char* p = ws + off;
    off = (off + bytes + 255) & ~(size_t)255;
    return p;
  };
  int* flag            = (int*)alloc(4);
  float* biasAll       = (float*)alloc(4096*4);
  unsigned short* wqt  = (unsigned short*)alloc((size_t)1024*1024*2);  // QKV weights contiguous
  unsigned short* wkt  = (unsigned short*)alloc((size_t)1024*1024*2);
  unsigned short* wvt  = (unsigned short*)alloc((size_t)1024*1024*2);
  unsigned short* wot  = (unsigned short*)alloc((size_t)1024*1024*2);
  unsigned short* hsb  = (unsigned short*)alloc((size_t)8192*1024*2);  // dead after QKV GEMM
  unsigned short* Qb   = (unsigned short*)alloc((size_t)16*8192*64*2); // [h][s][d^sw] *Cs
  unsigned short* Kb   = (unsigned short*)alloc((size_t)16*8192*64*2); // [h][s][d^sw]
  unsigned short* Vb   = (unsigned short*)alloc((size_t)16*8192*64*2); // [h][d][s'^sw]
  unsigned short* ctxb = hsb;                                          // alias (hsb dead)
  size_t base = off;
  const size_t PLANE = (size_t)8192*1024*4;          // 32 MB fp32
  const bool planes_fit = (ws_size >= base + 4*PLANE);

  k_detect<<<1, 256, 0, stream>>>((const unsigned*)d_in[0], flag);
  k_conv_bf16<<<4096, 256, 0, stream>>>(d_in[0], hsb, 8192*1024, flag);
  k_conv_wT4<<<dim3(32,32,4), 256, 0, stream>>>(d_in[1], d_in[3], d_in[5], d_in[7],
                                                wqt, wkt, wvt, wot, flag);
  k_conv_b4<<<16, 256, 0, stream>>>(d_in[2], d_in[4], d_in[6], d_in[8], biasAll, flag);

  const float Cs = 0.18033688011112042f;   // (1/8)*log2(e), folded into Q
  k_gemm<3><<<dim3(64, 24), 256, 0, stream>>>(hsb, wqt, biasAll, Qb, Kb, Vb, nullptr, Cs);

  if (planes_fit){
    float* part = (float*)(ws + base);               // 4 planes, 128 MB
    k_attn<0><<<2048, 512, 0, stream>>>(Qb, Kb, Vb, part);
    k_redux4<<<8192, 256, 0, stream>>>(part, ctxb);
  } else {
    float* ctxf = (float*)(ws + base);               // 32 MB accumulator
    k_zero<<<8192, 256, 0, stream>>>(ctxf);
    k_attn<1><<<2048, 512, 0, stream>>>(Qb, Kb, Vb, ctxf);
    k_cvt1<<<8192, 256, 0, stream>>>(ctxf, ctxb);
  }

  k_gemm<1><<<dim3(64, 8), 256, 0, stream>>>(ctxb, wot, biasAll + 3072, d_out,
                                             nullptr, nullptr, flag, 1.0f);
}